// Round 7
// baseline (181.803 us; speedup 1.0000x reference)
//
#include <hip/hip_runtime.h>

// out[b,n,m] = cost_class + cost_mask + cost_dice
//   dot[b,n,m] = sum_l sigmoid(p[b,n,l]) * t[b,m,l]   (bf16 MFMA, fp32 acc)
//   sum_p[b,n] = sum_l sigmoid(p)  (fp32, exact path)
//   sum_t[b,m] = sum_l t           (fp32, exact path)
//   cost_class = -logits[b,n,label[b,m]]
//   cost_mask  = -(2*dot + L - sum_p - sum_t)/L
//   cost_dice  = 1 - (2*dot + 1)/(sum_p + sum_t + 1)
//
// R7: block-sweep staging to minimize concurrent DRAM streams. All prior
// variants interleaved ~120 row-streams/block (60K+ chip-wide > HBM bank
// count -> page thrash at any burst size). Now: window=512 floats staged
// single-shot into 147KB LDS; each wave walks its rows IN ORDER with
// depth-2 prefetch -> per-block in-flight set is a contiguous ~16KB band
// sweeping forward (~4-8 streams/block). MFMA geometry/ws/fin unchanged.

#define Lsz 65536
#define Bb 4
#define Nn 100
#define Mm 20
#define Cc 81
#define WIN 512                 // floats per row per block (2KB row run)
#define NP 112                  // padded N stride in ws dot region
#define Pp (20 * NP + NP + 32)  // 2240 dot + 112 sum_p + 32 sum_t(padded) = 2384
#define KSTR 520                // LDS row stride in ushorts (512 bf16 + 8 pad; 1040B = 4 banks mod 32)
#define TPO 8                   // lanes cooperating per output in hung_fin

typedef short bf16x8 __attribute__((ext_vector_type(8)));
typedef float fx4 __attribute__((ext_vector_type(4)));
typedef float vf4 __attribute__((ext_vector_type(4)));  // native vec for nt loads

__device__ __forceinline__ float sigmoid_fast(float x) {
    float e = __builtin_amdgcn_exp2f(x * -1.44269504088896340736f);
    return __builtin_amdgcn_rcpf(1.0f + e);
}

__device__ __forceinline__ ushort bf16rne(float f) {
    union { float f; unsigned u; } v; v.f = f;
    unsigned u = v.u;
    u += 0x7fffu + ((u >> 16) & 1u);
    return (ushort)(u >> 16);
}

// LDS: A 112x520x2B = 116,480 + B 32x520x2B = 33,280 -> 149.8KB, 1 block/CU.
// (Rows A[100..111] / B[20..31] are never written; MFMA garbage from them
// lands only in discarded D rows/cols.)
__global__ __launch_bounds__(256) void hung_main(
    const float* __restrict__ pm,   // (B,N,L)
    const float* __restrict__ gm,   // (B,M,L)
    float* __restrict__ ws,         // (B,KBW,Pp)
    int KBW)
{
    __shared__ __align__(16) ushort ldsA[112 * KSTR];
    __shared__ __align__(16) ushort ldsB[32 * KSTR];

    const int tid  = threadIdx.x;
    const int slot = blockIdx.x;
    const int b    = blockIdx.y;
    const int lane = tid & 63;
    const int w    = tid >> 6;        // wave 0..3: row phase AND n-tile owner
    const int lr   = lane & 15;
    const int kg   = lane >> 4;       // 0..3

    float sp[25], st[5];
    #pragma unroll
    for (int p = 0; p < 25; ++p) sp[p] = 0.f;
    #pragma unroll
    for (int p = 0; p < 5; ++p) st[p] = 0.f;

    fx4 acc00 = {0.f, 0.f, 0.f, 0.f};
    fx4 acc01 = {0.f, 0.f, 0.f, 0.f};
    fx4 acc10 = {0.f, 0.f, 0.f, 0.f};
    fx4 acc11 = {0.f, 0.f, 0.f, 0.f};

    // lane covers floats [8*lane, 8*lane+8) of each owned row's window
    const float* pbase = pm + (size_t)b * Nn * Lsz + (size_t)w * Lsz
                            + (size_t)slot * WIN + 8 * lane;
    const float* tbase = gm + (size_t)b * Mm * Lsz + (size_t)w * Lsz
                            + (size_t)slot * WIN + 8 * lane;

    // ---- stage A: rows w+4p in ORDER, depth-2 row prefetch (sequential sweep)
    {
        vf4 c0 = __builtin_nontemporal_load((const vf4*)(pbase));
        vf4 c1 = __builtin_nontemporal_load((const vf4*)(pbase + 4));
        vf4 n0 = c0, n1 = c1;
        #pragma unroll
        for (int p = 0; p < 25; ++p) {
            if (p < 24) {
                const float* nx = pbase + (size_t)(4 * (p + 1)) * Lsz;
                n0 = __builtin_nontemporal_load((const vf4*)(nx));
                n1 = __builtin_nontemporal_load((const vf4*)(nx + 4));
            }
            const int r = w + 4 * p;
            float s0 = sigmoid_fast(c0.x), s1 = sigmoid_fast(c0.y);
            float s2 = sigmoid_fast(c0.z), s3 = sigmoid_fast(c0.w);
            float s4 = sigmoid_fast(c1.x), s5 = sigmoid_fast(c1.y);
            float s6 = sigmoid_fast(c1.z), s7 = sigmoid_fast(c1.w);
            sp[p] += ((s0 + s1) + (s2 + s3)) + ((s4 + s5) + (s6 + s7));
            ushort4 o0 = { bf16rne(s0), bf16rne(s1), bf16rne(s2), bf16rne(s3) };
            ushort4 o1 = { bf16rne(s4), bf16rne(s5), bf16rne(s6), bf16rne(s7) };
            *(ushort4*)&ldsA[r * KSTR + 8 * lane]     = o0;
            *(ushort4*)&ldsA[r * KSTR + 8 * lane + 4] = o1;
            c0 = n0; c1 = n1;
        }
    }
    // ---- stage B: rows w+4p in ORDER, depth-2 row prefetch
    {
        vf4 c0 = __builtin_nontemporal_load((const vf4*)(tbase));
        vf4 c1 = __builtin_nontemporal_load((const vf4*)(tbase + 4));
        vf4 n0 = c0, n1 = c1;
        #pragma unroll
        for (int p = 0; p < 5; ++p) {
            if (p < 4) {
                const float* nx = tbase + (size_t)(4 * (p + 1)) * Lsz;
                n0 = __builtin_nontemporal_load((const vf4*)(nx));
                n1 = __builtin_nontemporal_load((const vf4*)(nx + 4));
            }
            const int r = w + 4 * p;
            st[p] += ((c0.x + c0.y) + (c0.z + c0.w)) + ((c1.x + c1.y) + (c1.z + c1.w));
            ushort4 o0 = { bf16rne(c0.x), bf16rne(c0.y), bf16rne(c0.z), bf16rne(c0.w) };
            ushort4 o1 = { bf16rne(c1.x), bf16rne(c1.y), bf16rne(c1.z), bf16rne(c1.w) };
            *(ushort4*)&ldsB[r * KSTR + 8 * lane]     = o0;
            *(ushort4*)&ldsB[r * KSTR + 8 * lane + 4] = o1;
            c0 = n0; c1 = n1;
        }
    }
    __syncthreads();

    // ---- MFMA: 16 k-steps over the full 512-wide window
    #pragma unroll
    for (int ks = 0; ks < 16; ++ks) {
        const int ko = ks * 32 + kg * 8;  // ushort offset within row
        bf16x8 a0 = *(const bf16x8*)&ldsA[(32 * w + lr) * KSTR + ko];
        bf16x8 b0 = *(const bf16x8*)&ldsB[lr * KSTR + ko];
        bf16x8 b1 = *(const bf16x8*)&ldsB[(16 + lr) * KSTR + ko];
        acc00 = __builtin_amdgcn_mfma_f32_16x16x32_bf16(a0, b0, acc00, 0, 0, 0);
        acc01 = __builtin_amdgcn_mfma_f32_16x16x32_bf16(a0, b1, acc01, 0, 0, 0);
        if (w < 3) {  // n-tile 7 (rows 112..127) doesn't exist
            bf16x8 a1 = *(const bf16x8*)&ldsA[(32 * w + 16 + lr) * KSTR + ko];
            acc10 = __builtin_amdgcn_mfma_f32_16x16x32_bf16(a1, b0, acc10, 0, 0, 0);
            acc11 = __builtin_amdgcn_mfma_f32_16x16x32_bf16(a1, b1, acc11, 0, 0, 0);
        }
    }

    // ---- reduce sum_p / sum_t across all 64 lanes (row is wave-owned)
    #pragma unroll
    for (int p = 0; p < 25; ++p)
        #pragma unroll
        for (int o = 32; o > 0; o >>= 1) sp[p] += __shfl_xor(sp[p], o);
    #pragma unroll
    for (int p = 0; p < 5; ++p)
        #pragma unroll
        for (int o = 32; o > 0; o >>= 1) st[p] += __shfl_xor(st[p], o);

    float* wsb = ws + (size_t)(b * KBW + slot) * Pp;
    if (lane == 0) {
        #pragma unroll
        for (int p = 0; p < 25; ++p) wsb[20 * NP + (w + 4 * p)] = sp[p];
        #pragma unroll
        for (int p = 0; p < 5; ++p)  wsb[20 * NP + NP + (w + 4 * p)] = st[p];
    }

    // ---- store dot partials: D col = lane&15 (m), row = kg*4 + reg (n-local)
    const int nb = 32 * w + kg * 4;
    #pragma unroll
    for (int e = 0; e < 4; ++e) {
        const int n0 = nb + e;
        if (n0 < Nn) {
            wsb[lr * NP + n0] = acc00[e];
            if (lr < 4) wsb[(16 + lr) * NP + n0] = acc01[e];
        }
        const int n1 = nb + 16 + e;
        if (w < 3 && n1 < Nn) {
            wsb[lr * NP + n1] = acc10[e];
            if (lr < 4) wsb[(16 + lr) * NP + n1] = acc11[e];
        }
    }
}

// TPO=8 lanes team per output: 250 blocks, KBW/TPO-deep loop with unroll 8.
__global__ __launch_bounds__(256) void hung_fin(
    const float* __restrict__ ws,
    const float* __restrict__ logits,   // (B,N,C)
    const int*   __restrict__ labels,   // (B,M)
    float* __restrict__ out,            // (B,N,M)
    int KBW)
{
    const int gt   = blockIdx.x * 256 + threadIdx.x;
    const int oi   = gt / TPO;
    const int part = gt & (TPO - 1);
    if (oi >= Bb * Nn * Mm) return;
    const int b = oi / (Nn * Mm);
    const int r = oi % (Nn * Mm);
    const int m = r / Nn;       // n fast-varying -> coalesced-ish ws reads
    const int n = r % Nn;

    const float* p = ws + (size_t)(b * KBW + part) * Pp;
    const size_t step = (size_t)TPO * Pp;
    float dot = 0.f, sp = 0.f, st = 0.f;
    const int iters = KBW / TPO;
    #pragma unroll 8
    for (int j = 0; j < iters; ++j) {
        dot += p[m * NP + n];
        sp  += p[20 * NP + n];
        st  += p[20 * NP + NP + m];
        p += step;
    }

    #pragma unroll
    for (int o = TPO >> 1; o > 0; o >>= 1) {
        dot += __shfl_xor(dot, o);
        sp  += __shfl_xor(sp, o);
        st  += __shfl_xor(st, o);
    }

    if (part == 0) {
        int lab = labels[b * Mm + m];
        float cc = -logits[(size_t)(b * Nn + n) * Cc + lab];
        const float invL = 1.0f / (float)Lsz;
        float cm = -(2.f * dot + (float)Lsz - sp - st) * invL;
        float cd = 1.f - (2.f * dot + 1.f) / (sp + st + 1.f);
        out[(size_t)b * (Nn * Mm) + n * Mm + m] = cc + cm + cd;
    }
}

extern "C" void kernel_launch(void* const* d_in, const int* in_sizes, int n_in,
                              void* d_out, int out_size, void* d_ws, size_t ws_size,
                              hipStream_t stream) {
    const float* logits = (const float*)d_in[0];
    const float* pmasks = (const float*)d_in[1];
    const int*   labels = (const int*)d_in[2];
    const float* gmasks = (const float*)d_in[3];
    float* out = (float*)d_out;
    float* ws  = (float*)d_ws;

    const int KBW = Lsz / WIN;  // 128 slots; ws = 4.88 MB (fits)
    hung_main<<<dim3(KBW, Bb), 256, 0, stream>>>(pmasks, gmasks, ws, KBW);
    hung_fin<<<(Bb * Nn * Mm * TPO + 255) / 256, 256, 0, stream>>>(ws, logits, labels, out, KBW);
}

// Round 9
// 179.392 us; speedup vs baseline: 1.0134x; 1.0134x over previous
//
#include <hip/hip_runtime.h>

// out[b,n,m] = cost_class + cost_mask + cost_dice
//   dot[b,n,m] = sum_l sigmoid(p[b,n,l]) * t[b,m,l]   (bf16 MFMA, fp32 acc)
//   sum_p[b,n] = sum_l sigmoid(p)  (fp32, exact path)
//   sum_t[b,m] = sum_l t           (fp32, exact path)
//   cost_class = -logits[b,n,label[b,m]]
//   cost_mask  = -(2*dot + L - sum_p - sum_t)/L
//   cost_dice  = 1 - (2*dot + 1)/(sum_p + sum_t + 1)
//
// R9 = R4 (176.9us, passing) + ONE change: f32->bf16 packing via
// v_cvt_pk_bf16_f32 (2 instr/float4) instead of manual 4-op RNE per elem.
// Bisects R8's correctness failure (cvt_pk vs ones-sum) and tests the
// VALU-co-limit theory with minimal risk. Exact fp32 sum paths retained.

#define Lsz 65536
#define Bb 4
#define Nn 100
#define Mm 20
#define Cc 81
#define CS 128                  // l-chunk per staging pass
#define NP 112                  // padded N stride in ws dot region
#define Pp (20 * NP + NP + 32)  // 2240 dot + 112 sum_p + 32 sum_t(padded) = 2384
#define KSTR 136                // LDS row stride in ushorts (128 bf16 + 8 pad)
#define TPO 8                   // lanes cooperating per output in hung_fin

typedef short bf16x8 __attribute__((ext_vector_type(8)));
typedef float fx4 __attribute__((ext_vector_type(4)));
typedef float vf4 __attribute__((ext_vector_type(4)));  // native vec for nt loads

__device__ __forceinline__ float sigmoid_fast(float x) {
    float e = __builtin_amdgcn_exp2f(x * -1.44269504088896340736f);
    return __builtin_amdgcn_rcpf(1.0f + e);
}

// packed f32->bf16 RNE, 1 instr per 2 elements (T12 recipe; no builtin)
__device__ __forceinline__ unsigned cvt_pk_bf16(float lo, float hi) {
    unsigned r;
    asm("v_cvt_pk_bf16_f32 %0, %1, %2" : "=v"(r) : "v"(lo), "v"(hi));
    return r;
}

// 4 blocks/CU (LDS: 4 x 39.2KB = 157KB <= 160KB).
__global__ __launch_bounds__(256, 4) void hung_main(
    const float* __restrict__ pm,   // (B,N,L)
    const float* __restrict__ gm,   // (B,M,L)
    float* __restrict__ ws,         // (B,KBW,Pp)
    int KBW, int NCH)
{
    __shared__ __align__(16) ushort ldsA[NP * KSTR];  // sigma(p) bf16, [n][k]
    __shared__ __align__(16) ushort ldsB[32 * KSTR];  // t bf16, [m][k]

    const int tid  = threadIdx.x;
    const int slot = blockIdx.x;
    const int b    = blockIdx.y;
    const int q    = tid & 31;        // float4-quad within 128-float row chunk
    const int rr   = tid >> 5;        // 0..7, row phase
    const int lane = tid & 63;
    const int w    = tid >> 6;        // wave 0..3
    const int lr   = lane & 15;
    const int kg   = lane >> 4;       // 0..3

    float sp[13], st[3];
    #pragma unroll
    for (int p = 0; p < 13; ++p) sp[p] = 0.f;
    #pragma unroll
    for (int p = 0; p < 3; ++p) st[p] = 0.f;

    fx4 acc00 = {0.f, 0.f, 0.f, 0.f};
    fx4 acc01 = {0.f, 0.f, 0.f, 0.f};
    fx4 acc10 = {0.f, 0.f, 0.f, 0.f};
    fx4 acc11 = {0.f, 0.f, 0.f, 0.f};

    const float* pbase = pm + (size_t)b * Nn * Lsz + 4 * q;
    const float* tbase = gm + (size_t)b * Mm * Lsz + 4 * q;

    for (int c = 0; c < NCH; ++c) {
        const int l0 = (slot * NCH + c) * CS;
        __syncthreads();  // prev chunk's LDS reads done before overwrite

        // ---- stage A: sigma(pred_masks) -> bf16 LDS [n][k]  (nt: read-once)
        #pragma unroll
        for (int p = 0; p < 13; ++p) {
            const int r = rr + 8 * p;
            if (r < Nn) {
                vf4 v = __builtin_nontemporal_load(
                    (const vf4*)(pbase + (size_t)r * Lsz + l0));
                float s0 = sigmoid_fast(v.x), s1 = sigmoid_fast(v.y);
                float s2 = sigmoid_fast(v.z), s3 = sigmoid_fast(v.w);
                sp[p] += (s0 + s1) + (s2 + s3);
                uint2 o = { cvt_pk_bf16(s0, s1), cvt_pk_bf16(s2, s3) };
                *(uint2*)&ldsA[r * KSTR + 4 * q] = o;
            }
        }
        // ---- stage B: gt_masks -> bf16 LDS [m][k]  (nt: read-once)
        #pragma unroll
        for (int p = 0; p < 3; ++p) {
            const int r = rr + 8 * p;
            if (r < Mm) {
                vf4 v = __builtin_nontemporal_load(
                    (const vf4*)(tbase + (size_t)r * Lsz + l0));
                st[p] += (v.x + v.y) + (v.z + v.w);
                uint2 o = { cvt_pk_bf16(v.x, v.y), cvt_pk_bf16(v.z, v.w) };
                *(uint2*)&ldsB[r * KSTR + 4 * q] = o;
            }
        }
        __syncthreads();

        // ---- MFMA: wave w owns n-tiles {2w, 2w+1}, m-tiles {0,1}
        #pragma unroll
        for (int kk = 0; kk < 4; ++kk) {
            const int ko = kk * 32 + kg * 8;  // ushort offset within row
            bf16x8 a0 = *(const bf16x8*)&ldsA[(32 * w + lr) * KSTR + ko];
            bf16x8 b0 = *(const bf16x8*)&ldsB[lr * KSTR + ko];
            bf16x8 b1 = *(const bf16x8*)&ldsB[(16 + lr) * KSTR + ko];
            acc00 = __builtin_amdgcn_mfma_f32_16x16x32_bf16(a0, b0, acc00, 0, 0, 0);
            acc01 = __builtin_amdgcn_mfma_f32_16x16x32_bf16(a0, b1, acc01, 0, 0, 0);
            if (w < 3) {  // n-tile 7 (rows 112..127) doesn't exist
                bf16x8 a1 = *(const bf16x8*)&ldsA[(32 * w + 16 + lr) * KSTR + ko];
                acc10 = __builtin_amdgcn_mfma_f32_16x16x32_bf16(a1, b0, acc10, 0, 0, 0);
                acc11 = __builtin_amdgcn_mfma_f32_16x16x32_bf16(a1, b1, acc11, 0, 0, 0);
            }
        }
    }

    // ---- reduce sum_p / sum_t across the 32 q-lanes of each row group
    #pragma unroll
    for (int p = 0; p < 13; ++p)
        #pragma unroll
        for (int o = 16; o > 0; o >>= 1) sp[p] += __shfl_xor(sp[p], o, 32);
    #pragma unroll
    for (int p = 0; p < 3; ++p)
        #pragma unroll
        for (int o = 16; o > 0; o >>= 1) st[p] += __shfl_xor(st[p], o, 32);

    float* wsb = ws + (size_t)(b * KBW + slot) * Pp;
    if ((tid & 31) == 0) {
        #pragma unroll
        for (int p = 0; p < 13; ++p) {
            const int r = rr + 8 * p;
            if (r < Nn) wsb[20 * NP + r] = sp[p];
        }
        #pragma unroll
        for (int p = 0; p < 3; ++p) {
            const int r = rr + 8 * p;
            if (r < Mm) wsb[20 * NP + NP + r] = st[p];
        }
    }

    // ---- store dot partials: D col = lane&15 (m), row = kg*4 + reg (n-local)
    const int nb = 32 * w + kg * 4;
    #pragma unroll
    for (int e = 0; e < 4; ++e) {
        const int n0 = nb + e;
        if (n0 < Nn) {
            wsb[lr * NP + n0] = acc00[e];
            if (lr < 4) wsb[(16 + lr) * NP + n0] = acc01[e];
        }
        const int n1 = nb + 16 + e;
        if (w < 3 && n1 < Nn) {
            wsb[lr * NP + n1] = acc10[e];
            if (lr < 4) wsb[(16 + lr) * NP + n1] = acc11[e];
        }
    }
}

// TPO=8 lanes team up per output: 250 blocks, KBW/TPO-deep loop with
// unroll 8 -> many loads in flight, few dependent rounds.
__global__ __launch_bounds__(256) void hung_fin(
    const float* __restrict__ ws,
    const float* __restrict__ logits,   // (B,N,C)
    const int*   __restrict__ labels,   // (B,M)
    float* __restrict__ out,            // (B,N,M)
    int KBW)
{
    const int gt   = blockIdx.x * 256 + threadIdx.x;
    const int oi   = gt / TPO;
    const int part = gt & (TPO - 1);
    if (oi >= Bb * Nn * Mm) return;
    const int b = oi / (Nn * Mm);
    const int r = oi % (Nn * Mm);
    const int m = r / Nn;       // n fast-varying -> coalesced-ish ws reads
    const int n = r % Nn;

    const float* p = ws + (size_t)(b * KBW + part) * Pp;
    const size_t step = (size_t)TPO * Pp;
    float dot = 0.f, sp = 0.f, st = 0.f;
    const int iters = KBW / TPO;
    #pragma unroll 8
    for (int j = 0; j < iters; ++j) {
        dot += p[m * NP + n];
        sp  += p[20 * NP + n];
        st  += p[20 * NP + NP + m];
        p += step;
    }

    #pragma unroll
    for (int o = TPO >> 1; o > 0; o >>= 1) {
        dot += __shfl_xor(dot, o);
        sp  += __shfl_xor(sp, o);
        st  += __shfl_xor(st, o);
    }

    if (part == 0) {
        int lab = labels[b * Mm + m];
        float cc = -logits[(size_t)(b * Nn + n) * Cc + lab];
        const float invL = 1.0f / (float)Lsz;
        float cm = -(2.f * dot + (float)Lsz - sp - st) * invL;
        float cd = 1.f - (2.f * dot + 1.f) / (sp + st + 1.f);
        out[(size_t)b * (Nn * Mm) + n * Mm + m] = cc + cm + cd;
    }
}

extern "C" void kernel_launch(void* const* d_in, const int* in_sizes, int n_in,
                              void* d_out, int out_size, void* d_ws, size_t ws_size,
                              hipStream_t stream) {
    const float* logits = (const float*)d_in[0];
    const float* pmasks = (const float*)d_in[1];
    const int*   labels = (const int*)d_in[2];
    const float* gmasks = (const float*)d_in[3];
    float* out = (float*)d_out;
    float* ws  = (float*)d_ws;

    int KBW = 256;  // split-K slots per batch: grid 1024 = 4 blocks/CU
    while (KBW > 1 && (size_t)Bb * KBW * Pp * sizeof(float) > ws_size) KBW >>= 1;
    int NCH = (Lsz / CS) / KBW;  // chunks per block (2 at KBW=256)

    hung_main<<<dim3(KBW, Bb), 256, 0, stream>>>(pmasks, gmasks, ws, KBW, NCH);
    hung_fin<<<(Bb * Nn * Mm * TPO + 255) / 256, 256, 0, stream>>>(ws, logits, labels, out, KBW);
}

// Round 11
// 175.552 us; speedup vs baseline: 1.0356x; 1.0219x over previous
//
#include <hip/hip_runtime.h>

// out[b,n,m] = cost_class + cost_mask + cost_dice
//   dot[b,n,m] = sum_l sigmoid(p[b,n,l]) * t[b,m,l]   (bf16 MFMA, fp32 acc)
//   sum_p[b,n] = sum_l sigmoid(p)  (fp32, exact path)
//   sum_t[b,m] = sum_l t           (fp32, exact path)
//   cost_class = -logits[b,n,label[b,m]]
//   cost_mask  = -(2*dot + L - sum_p - sum_t)/L
//   cost_dice  = 1 - (2*dot + 1)/(sp + st + 1)
//
// R11 = R4 verbatim (best measured: 176.9us, passing). Restores the proven
// optimum after R10's cooperative-launch container failure. Session ladder:
// 200.9 -> 187.9 (fin TPO=8 teams) -> 176.9 (nontemporal loads). main's
// ~49us proved invariant to 8 structural levers (occupancy, pipelining,
// burst size, stream count, packing, split-K width); the 2x61.5us harness
// ws-poison fills (86% HBM peak) dominate the remaining timed window.

#define Lsz 65536
#define Bb 4
#define Nn 100
#define Mm 20
#define Cc 81
#define CS 128                  // l-chunk per staging pass
#define NP 112                  // padded N stride in ws dot region
#define Pp (20 * NP + NP + 32)  // 2240 dot + 112 sum_p + 32 sum_t(padded) = 2384
#define KSTR 136                // LDS row stride in ushorts (128 bf16 + 8 pad)
#define TPO 8                   // lanes cooperating per output in hung_fin

typedef short bf16x8 __attribute__((ext_vector_type(8)));
typedef float fx4 __attribute__((ext_vector_type(4)));
typedef float vf4 __attribute__((ext_vector_type(4)));  // native vec for nt loads

__device__ __forceinline__ float sigmoid_fast(float x) {
    float e = __builtin_amdgcn_exp2f(x * -1.44269504088896340736f);
    return __builtin_amdgcn_rcpf(1.0f + e);
}

__device__ __forceinline__ ushort bf16rne(float f) {
    union { float f; unsigned u; } v; v.f = f;
    unsigned u = v.u;
    u += 0x7fffu + ((u >> 16) & 1u);
    return (ushort)(u >> 16);
}

// 4 blocks/CU (LDS: 4 x 39.2KB = 157KB <= 160KB).
__global__ __launch_bounds__(256, 4) void hung_main(
    const float* __restrict__ pm,   // (B,N,L)
    const float* __restrict__ gm,   // (B,M,L)
    float* __restrict__ ws,         // (B,KBW,Pp)
    int KBW, int NCH)
{
    __shared__ __align__(16) ushort ldsA[NP * KSTR];  // sigma(p) bf16, [n][k]
    __shared__ __align__(16) ushort ldsB[32 * KSTR];  // t bf16, [m][k]

    const int tid  = threadIdx.x;
    const int slot = blockIdx.x;
    const int b    = blockIdx.y;
    const int q    = tid & 31;        // float4-quad within 128-float row chunk
    const int rr   = tid >> 5;        // 0..7, row phase
    const int lane = tid & 63;
    const int w    = tid >> 6;        // wave 0..3
    const int lr   = lane & 15;
    const int kg   = lane >> 4;       // 0..3

    float sp[13], st[3];
    #pragma unroll
    for (int p = 0; p < 13; ++p) sp[p] = 0.f;
    #pragma unroll
    for (int p = 0; p < 3; ++p) st[p] = 0.f;

    fx4 acc00 = {0.f, 0.f, 0.f, 0.f};
    fx4 acc01 = {0.f, 0.f, 0.f, 0.f};
    fx4 acc10 = {0.f, 0.f, 0.f, 0.f};
    fx4 acc11 = {0.f, 0.f, 0.f, 0.f};

    const float* pbase = pm + (size_t)b * Nn * Lsz + 4 * q;
    const float* tbase = gm + (size_t)b * Mm * Lsz + 4 * q;

    for (int c = 0; c < NCH; ++c) {
        const int l0 = (slot * NCH + c) * CS;
        __syncthreads();  // prev chunk's LDS reads done before overwrite

        // ---- stage A: sigma(pred_masks) -> bf16 LDS [n][k]  (nt: read-once)
        #pragma unroll
        for (int p = 0; p < 13; ++p) {
            const int r = rr + 8 * p;
            if (r < Nn) {
                vf4 v = __builtin_nontemporal_load(
                    (const vf4*)(pbase + (size_t)r * Lsz + l0));
                float s0 = sigmoid_fast(v.x), s1 = sigmoid_fast(v.y);
                float s2 = sigmoid_fast(v.z), s3 = sigmoid_fast(v.w);
                sp[p] += (s0 + s1) + (s2 + s3);
                ushort4 o = { bf16rne(s0), bf16rne(s1), bf16rne(s2), bf16rne(s3) };
                *(ushort4*)&ldsA[r * KSTR + 4 * q] = o;
            }
        }
        // ---- stage B: gt_masks -> bf16 LDS [m][k]  (nt: read-once)
        #pragma unroll
        for (int p = 0; p < 3; ++p) {
            const int r = rr + 8 * p;
            if (r < Mm) {
                vf4 v = __builtin_nontemporal_load(
                    (const vf4*)(tbase + (size_t)r * Lsz + l0));
                st[p] += (v.x + v.y) + (v.z + v.w);
                ushort4 o = { bf16rne(v.x), bf16rne(v.y), bf16rne(v.z), bf16rne(v.w) };
                *(ushort4*)&ldsB[r * KSTR + 4 * q] = o;
            }
        }
        __syncthreads();

        // ---- MFMA: wave w owns n-tiles {2w, 2w+1}, m-tiles {0,1}
        #pragma unroll
        for (int kk = 0; kk < 4; ++kk) {
            const int ko = kk * 32 + kg * 8;  // ushort offset within row
            bf16x8 a0 = *(const bf16x8*)&ldsA[(32 * w + lr) * KSTR + ko];
            bf16x8 b0 = *(const bf16x8*)&ldsB[lr * KSTR + ko];
            bf16x8 b1 = *(const bf16x8*)&ldsB[(16 + lr) * KSTR + ko];
            acc00 = __builtin_amdgcn_mfma_f32_16x16x32_bf16(a0, b0, acc00, 0, 0, 0);
            acc01 = __builtin_amdgcn_mfma_f32_16x16x32_bf16(a0, b1, acc01, 0, 0, 0);
            if (w < 3) {  // n-tile 7 (rows 112..127) doesn't exist
                bf16x8 a1 = *(const bf16x8*)&ldsA[(32 * w + 16 + lr) * KSTR + ko];
                acc10 = __builtin_amdgcn_mfma_f32_16x16x32_bf16(a1, b0, acc10, 0, 0, 0);
                acc11 = __builtin_amdgcn_mfma_f32_16x16x32_bf16(a1, b1, acc11, 0, 0, 0);
            }
        }
    }

    // ---- reduce sum_p / sum_t across the 32 q-lanes of each row group
    #pragma unroll
    for (int p = 0; p < 13; ++p)
        #pragma unroll
        for (int o = 16; o > 0; o >>= 1) sp[p] += __shfl_xor(sp[p], o, 32);
    #pragma unroll
    for (int p = 0; p < 3; ++p)
        #pragma unroll
        for (int o = 16; o > 0; o >>= 1) st[p] += __shfl_xor(st[p], o, 32);

    float* wsb = ws + (size_t)(b * KBW + slot) * Pp;
    if ((tid & 31) == 0) {
        #pragma unroll
        for (int p = 0; p < 13; ++p) {
            const int r = rr + 8 * p;
            if (r < Nn) wsb[20 * NP + r] = sp[p];
        }
        #pragma unroll
        for (int p = 0; p < 3; ++p) {
            const int r = rr + 8 * p;
            if (r < Mm) wsb[20 * NP + NP + r] = st[p];
        }
    }

    // ---- store dot partials: D col = lane&15 (m), row = kg*4 + reg (n-local)
    const int nb = 32 * w + kg * 4;
    #pragma unroll
    for (int e = 0; e < 4; ++e) {
        const int n0 = nb + e;
        if (n0 < Nn) {
            wsb[lr * NP + n0] = acc00[e];
            if (lr < 4) wsb[(16 + lr) * NP + n0] = acc01[e];
        }
        const int n1 = nb + 16 + e;
        if (w < 3 && n1 < Nn) {
            wsb[lr * NP + n1] = acc10[e];
            if (lr < 4) wsb[(16 + lr) * NP + n1] = acc11[e];
        }
    }
}

// TPO=8 lanes team up per output: 250 blocks, KBW/TPO-deep loop with
// unroll 8 -> many loads in flight, few dependent rounds.
__global__ __launch_bounds__(256) void hung_fin(
    const float* __restrict__ ws,
    const float* __restrict__ logits,   // (B,N,C)
    const int*   __restrict__ labels,   // (B,M)
    float* __restrict__ out,            // (B,N,M)
    int KBW)
{
    const int gt   = blockIdx.x * 256 + threadIdx.x;
    const int oi   = gt / TPO;
    const int part = gt & (TPO - 1);
    if (oi >= Bb * Nn * Mm) return;
    const int b = oi / (Nn * Mm);
    const int r = oi % (Nn * Mm);
    const int m = r / Nn;       // n fast-varying -> coalesced-ish ws reads
    const int n = r % Nn;

    const float* p = ws + (size_t)(b * KBW + part) * Pp;
    const size_t step = (size_t)TPO * Pp;
    float dot = 0.f, sp = 0.f, st = 0.f;
    const int iters = KBW / TPO;
    #pragma unroll 8
    for (int j = 0; j < iters; ++j) {
        dot += p[m * NP + n];
        sp  += p[20 * NP + n];
        st  += p[20 * NP + NP + m];
        p += step;
    }

    #pragma unroll
    for (int o = TPO >> 1; o > 0; o >>= 1) {
        dot += __shfl_xor(dot, o);
        sp  += __shfl_xor(sp, o);
        st  += __shfl_xor(st, o);
    }

    if (part == 0) {
        int lab = labels[b * Mm + m];
        float cc = -logits[(size_t)(b * Nn + n) * Cc + lab];
        const float invL = 1.0f / (float)Lsz;
        float cm = -(2.f * dot + (float)Lsz - sp - st) * invL;
        float cd = 1.f - (2.f * dot + 1.f) / (sp + st + 1.f);
        out[(size_t)b * (Nn * Mm) + n * Mm + m] = cc + cm + cd;
    }
}

extern "C" void kernel_launch(void* const* d_in, const int* in_sizes, int n_in,
                              void* d_out, int out_size, void* d_ws, size_t ws_size,
                              hipStream_t stream) {
    const float* logits = (const float*)d_in[0];
    const float* pmasks = (const float*)d_in[1];
    const int*   labels = (const int*)d_in[2];
    const float* gmasks = (const float*)d_in[3];
    float* out = (float*)d_out;
    float* ws  = (float*)d_ws;

    int KBW = 256;  // split-K slots per batch: grid 1024 = 4 blocks/CU
    while (KBW > 1 && (size_t)Bb * KBW * Pp * sizeof(float) > ws_size) KBW >>= 1;
    int NCH = (Lsz / CS) / KBW;  // chunks per block (2 at KBW=256)

    hung_main<<<dim3(KBW, Bb), 256, 0, stream>>>(pmasks, gmasks, ws, KBW, NCH);
    hung_fin<<<(Bb * Nn * Mm * TPO + 255) / 256, 256, 0, stream>>>(ws, logits, labels, out, KBW);
}